// Round 8
// baseline (97.626 us; speedup 1.0000x reference)
//
#include <hip/hip_runtime.h>
#include <math.h>

// GP_conv2D: N=8, IH=IW=32, IC=8, OC=16, 3x3 s1 p1, P=5, I_DIM=72
#define OC_N   16
#define I_DIM  72
#define PN     5
#define NEU    (OC_N * I_DIM)   // 1152
#define NF     32               // floats per neuron record (128 B)
#define RTOT   8192             // N * OH * OW
#define OUT_HALF (RTOT * OC_N)  // 131072
#define LOG2E  1.4426950408889634f
#define RLOG2E 0.6931471805599453f

#if __has_builtin(__builtin_amdgcn_rcpf)
#define RCPF(x) __builtin_amdgcn_rcpf(x)
#else
#define RCPF(x) (1.0f / (x))
#endif
#if __has_builtin(__builtin_amdgcn_exp2f)
#define EXP2F(x) __builtin_amdgcn_exp2f(x)
#else
#define EXP2F(x) exp2f(x)
#endif
#if __has_builtin(__builtin_amdgcn_logf)
#define LOG2F(x) __builtin_amdgcn_logf(x)
#else
#define LOG2F(x) log2f(x)
#endif
#if __has_builtin(__builtin_amdgcn_rsqf)
#define RSQF(x) __builtin_amdgcn_rsqf(x)
#else
#define RSQF(x) rsqrtf(x)
#endif

// Neuron record layout (32 floats):
// [0]=l2  [1]=pad  [2..6]=z[p]  [7..11]=alpha[p]
// [12..16]=Kinv diag  [17..26]=2*Kinv offdiag (01,02,03,04,12,13,14,23,24,34)

__global__ __launch_bounds__(256) void gp_prep_kernel(
    const float* __restrict__ zin, const float* __restrict__ hin,
    const float* __restrict__ rlin, float* __restrict__ nr) {
  int idx = blockIdx.x * blockDim.x + threadIdx.x;
  if (idx >= NEU) return;
  float x  = rlin[idx];
  float t  = EXP2F(-fabsf(x) * LOG2E);
  float sp = fmaxf(x, 0.0f) + LOG2F(1.0f + t) * RLOG2E;
  float l2 = sp * sp;
  float cexp = -0.5f * LOG2E * RCPF(l2);

  float zz[PN], hh[PN];
#pragma unroll
  for (int p = 0; p < PN; ++p) {
    zz[p] = zin[idx * PN + p];
    hh[p] = hin[idx * PN + p];
  }
  float A[PN][PN], B[PN][PN];
#pragma unroll
  for (int p = 0; p < PN; ++p) {
#pragma unroll
    for (int q = 0; q < PN; ++q) {
      float dz = zz[p] - zz[q];
      A[p][q] = EXP2F(cexp * dz * dz);
      B[p][q] = (p == q) ? 1.0f : 0.0f;
    }
  }
#pragma unroll
  for (int p = 0; p < PN; ++p) A[p][p] += 1e-4f;

#pragma unroll
  for (int c = 0; c < PN; ++c) {
    float pivinv = RCPF(A[c][c]);
#pragma unroll
    for (int j = 0; j < PN; ++j) { A[c][j] *= pivinv; B[c][j] *= pivinv; }
#pragma unroll
    for (int r = 0; r < PN; ++r) {
      if (r == c) continue;
      float f = A[r][c];
#pragma unroll
      for (int j = 0; j < PN; ++j) { A[r][j] -= f * A[c][j]; B[r][j] -= f * B[c][j]; }
    }
  }
  float alpha[PN];
#pragma unroll
  for (int p = 0; p < PN; ++p) {
    float s = 0.0f;
#pragma unroll
    for (int q = 0; q < PN; ++q) s += B[p][q] * hh[q];
    alpha[p] = s;
  }
  float* o = nr + idx * NF;
  o[0] = l2;
  o[1] = 0.0f;
#pragma unroll
  for (int p = 0; p < PN; ++p) {
    o[2 + p]  = zz[p];
    o[7 + p]  = alpha[p];
    o[12 + p] = B[p][p];
  }
  int j = 17;
#pragma unroll
  for (int p = 0; p < PN; ++p)
#pragma unroll
    for (int q = p + 1; q < PN; ++q) o[j++] = 2.0f * B[p][q];
  o[27] = o[28] = o[29] = o[30] = o[31] = 0.0f;
}

// Main: 4-wave blocks, generous VGPR budget (__launch_bounds__(256,2) ->
// up to 256 VGPRs), per-lane VGPR-resident params, coalesced dword loads.
// Block = 256 thr = 4 waves, all on tap k=blockIdx.z, channel o=blockIdx.y.
// Lane = (rlo = lane>>3, c = lane&7); wave wy handles rows
// rblk + it*32 + wy*8 + rlo over 8 iterations (256 rows per block).
__global__ __launch_bounds__(256, 2) void gp_main_kernel(
    const float* __restrict__ xm, const float* __restrict__ xv,
    const float* __restrict__ nr, float2* __restrict__ pmq) {
  const int tx   = threadIdx.x;
  const int lane = tx & 63;
  const int wy   = tx >> 6;                    // wave 0..3
  const int rlo  = lane >> 3;                  // 0..7
  const int c    = lane & 7;
  const int k  = blockIdx.z;                   // tap 0..8 (uniform)
  const int kh = k / 3;
  const int kw = k - kh * 3;
  const int o  = blockIdx.y;
  const int rblk = blockIdx.x * 256;           // 256 rows per block

  // ---- per-lane params, 7 x float4 loads, VGPR-resident ----
  float P[28];
  {
    const float4* rec4 = (const float4*)(nr + (o * I_DIM + (c * 9 + k)) * NF);
#pragma unroll
    for (int j = 0; j < 7; ++j) *(float4*)&P[4 * j] = rec4[j];
  }
  const float l2 = P[0];

#pragma unroll
  for (int it = 0; it < 8; ++it) {
    const int r8  = rblk + it * 32 + wy * 8;   // uniform per wave, mult of 8
    const int n   = r8 >> 10;
    const int pix = r8 & 1023;
    const int oh  = pix >> 5;
    const int ow0 = pix & 31;                  // multiple of 8
    const int ih  = oh + kh - 1;               // uniform per wave
    const int iw  = ow0 + rlo + kw - 1;        // per-lane
    const bool valid = ((unsigned)ih < 32u) & ((unsigned)iw < 32u);
    const int ihc = ih < 0 ? 0 : (ih > 31 ? 31 : ih);
    const int iwc = iw < 0 ? 0 : (iw > 31 ? 31 : iw);
    const int addr = ((n * 32 + ihc) * 32 + iwc) * 8 + c;  // coalesced
    float m = xm[addr];
    float s = xv[addr];
    m = valid ? m : 0.0f;
    s = valid ? s : 0.0f;

    const float d     = l2 + s;
    const float inv_d = RCPF(d);
    const float coef2 = l2 * inv_d;            // l2/d
    const float coef  = coef2 * RSQF(coef2);   // sqrt(coef2), raw v_rsq
    const float el    = -0.72134752044f * inv_d; // -0.5*log2(e)/d
    const float d0 = m - P[2];
    const float d1 = m - P[3];
    const float d2 = m - P[4];
    const float d3 = m - P[5];
    const float d4 = m - P[6];
    const float u0 = EXP2F(el * d0 * d0);
    const float u1 = EXP2F(el * d1 * d1);
    const float u2 = EXP2F(el * d2 * d2);
    const float u3 = EXP2F(el * d3 * d3);
    const float u4 = EXP2F(el * d4 * d4);
    const float dotA =
        fmaf(u0, P[7], fmaf(u1, P[8], fmaf(u2, P[9], fmaf(u3, P[10], u4 * P[11]))));
    const float t0 = fmaf(P[12], u0, fmaf(P[17], u1, fmaf(P[18], u2, fmaf(P[19], u3, P[20] * u4))));
    const float t1 = fmaf(P[13], u1, fmaf(P[21], u2, fmaf(P[22], u3, P[23] * u4)));
    const float t2 = fmaf(P[14], u2, fmaf(P[24], u3, P[25] * u4));
    const float t3 = fmaf(P[15], u3, P[26] * u4);
    const float t4 = P[16] * u4;
    const float quad =
        fmaf(u0, t0, fmaf(u1, t1, fmaf(u2, t2, fmaf(u3, t3, u4 * t4))));
    float mean = coef * dotA;
    float qkq  = coef2 * quad;

    // reduce over c (low 3 lane bits)
    mean += __shfl_xor(mean, 1); qkq += __shfl_xor(qkq, 1);
    mean += __shfl_xor(mean, 2); qkq += __shfl_xor(qkq, 2);
    mean += __shfl_xor(mean, 4); qkq += __shfl_xor(qkq, 4);

    if (c == 0)
      pmq[(size_t)(k * OC_N + o) * RTOT + (r8 + rlo)] = make_float2(mean, qkq);
  }
}

// Coalesced reads of 9 partials; strided 4B out-stores (cheap).
__global__ __launch_bounds__(256) void gp_final_kernel(
    const float2* __restrict__ pmq, float* __restrict__ out) {
  const int j = blockIdx.x * 256 + threadIdx.x;   // 0..131071
  const int o = j >> 13;
  const int r = j & 8191;
  float m = 0.0f, q = 0.0f;
#pragma unroll
  for (int s = 0; s < 9; ++s) {
    const float2 v = pmq[(size_t)(s * OC_N + o) * RTOT + r];
    m += v.x;
    q += v.y;
  }
  const int i = r * OC_N + o;
  out[i] = m;
  out[OUT_HALF + i] = fmaxf(72.0f - q, 1e-6f);
}

extern "C" void kernel_launch(void* const* d_in, const int* in_sizes, int n_in,
                              void* d_out, int out_size, void* d_ws, size_t ws_size,
                              hipStream_t stream) {
  const float* xm = (const float*)d_in[0];   // x_mean [8,32,32,8]
  const float* xv = (const float*)d_in[1];   // x_var  [8,32,32,8]
  const float* z  = (const float*)d_in[2];   // [16,72,5]
  const float* h  = (const float*)d_in[3];   // [16,72,5]
  const float* rl = (const float*)d_in[4];   // [16,72]
  float* out = (float*)d_out;                // mean(131072) ++ var(131072)

  float* nr   = (float*)d_ws;                // 147456 B
  float2* pmq = (float2*)((char*)d_ws + NEU * NF * 4);  // 9*16*8192 float2

  gp_prep_kernel<<<dim3((NEU + 255) / 256), dim3(256), 0, stream>>>(z, h, rl, nr);

  dim3 grid(RTOT / 256, OC_N, 9);            // (32, 16, 9) = 4608 4-wave blocks
  gp_main_kernel<<<grid, dim3(256), 0, stream>>>(xm, xv, nr, pmq);

  gp_final_kernel<<<dim3(OUT_HALF / 256), dim3(256), 0, stream>>>(pmq, out);
}